// Round 2
// baseline (440.893 us; speedup 1.0000x reference)
//
#include <hip/hip_runtime.h>
#include <stdint.h>

#define CH    256
#define HWsz  3136
#define NIMG  32
#define COLS  (NIMG * HWsz)   // 100352
#define KB    32
#define TN    64

typedef float  f32x4  __attribute__((ext_vector_type(4)));
typedef __bf16 bf16x8 __attribute__((ext_vector_type(8)));

struct Stats {
  float mnsum[CH];
  float mn[CH];
  float poff[CH];
  float clF[CH];
  unsigned dminK[CH];
  unsigned dmaxK[CH];
  float dminF[CH];
  float scaleF[CH];
  float invF[CH];
  float qsum[CH];
  float corr[CH];
  unsigned short u_bf[CH * CH];   // u row-major (A for GEMM2)
  unsigned short uT_bf[CH * CH];  // u transposed (A for GEMM1)
};

__device__ __forceinline__ unsigned short f2bf(float f) {
  union { float f; unsigned u; } v; v.f = f;
  unsigned r = v.u + 0x7fffu + ((v.u >> 16) & 1u);  // RNE
  return (unsigned short)(r >> 16);
}
__device__ __forceinline__ float bf2f(unsigned short b) {
  union { unsigned u; float f; } v; v.u = ((unsigned)b) << 16;
  return v.f;
}
__device__ __forceinline__ unsigned pack_bf2(float a, float b) {
  return (unsigned)f2bf(a) | ((unsigned)f2bf(b) << 16);
}
__device__ __forceinline__ unsigned fkey(float f) {  // monotonic float->uint
  unsigned u = __float_as_uint(f);
  return (u & 0x80000000u) ? ~u : (u | 0x80000000u);
}
__device__ __forceinline__ float funkey(unsigned k) {
  unsigned u = (k & 0x80000000u) ? (k & 0x7fffffffu) : ~k;
  return __uint_as_float(u);
}
__device__ __forceinline__ float clampf(float v, float c) {
  return fminf(fmaxf(v, -c), c);
}
__device__ __forceinline__ float dq(float v, float dmin, float sc, float inv) {
  return sc == 0.f ? v : fmaf(rintf((v - dmin) * sc), inv, dmin);
}

// ---- init: convert u to bf16 (both layouts), zero accumulators ----------
__global__ void k_init(const float* __restrict__ u, Stats* st) {
  int b = blockIdx.x, t = threadIdx.x;
  st->u_bf[b * CH + t]  = f2bf(u[b * CH + t]);
  st->uT_bf[b * CH + t] = f2bf(u[t * CH + b]);
  if (b == 0) {
    st->mnsum[t] = 0.f;
    st->qsum[t]  = 0.f;
    st->dminK[t] = 0xFFFFFFFFu;
    st->dmaxK[t] = 0u;
  }
}

// ---- GEMM1: p' = uT @ relu(x) (raw), fused relu-channel-sums + raw row min/max
// ILV: p' stored as u32[n][kp][col] (bf16 row-pair). else fp32 [n][row][col].
template <bool ILV>
__global__ __launch_bounds__(256) void k_gemm1(const float* __restrict__ x,
                                               Stats* __restrict__ st,
                                               void* __restrict__ pqv) {
  __shared__ __align__(16) unsigned ldsB[2][TN * 20];
  __shared__ float smin[CH];
  __shared__ float smax[CH];

  const int blk = blockIdx.x;
  const int n   = blk / (HWsz / TN);
  const int hw0 = (blk % (HWsz / TN)) * TN;
  const int t = threadIdx.x;
  const int lane = t & 63, wv = t >> 6;
  const int g = t & 15, cpair = t >> 4;
  const int sq = cpair >> 2, c2 = cpair & 3;
  const int q = lane >> 4, r15 = lane & 15;

  const float* xb = x + (size_t)n * CH * HWsz + hw0 + 4 * g;
  const unsigned short* uT = st->uT_bf;

  f32x4 acc[4][4] = {};
  float4 va, vb;

  auto ldrows = [&](int kc, float4& A, float4& B) {
    const float* r0 = xb + (size_t)(kc * KB + 2 * cpair) * HWsz;
    A = *(const float4*)r0;
    B = *(const float4*)(r0 + HWsz);
  };
  auto stage = [&](int kc, int buf, float4 A, float4 B) {
    float a[4] = {fmaxf(A.x, 0.f), fmaxf(A.y, 0.f), fmaxf(A.z, 0.f), fmaxf(A.w, 0.f)};
    float b[4] = {fmaxf(B.x, 0.f), fmaxf(B.y, 0.f), fmaxf(B.z, 0.f), fmaxf(B.w, 0.f)};
    float s0 = (a[0] + a[1]) + (a[2] + a[3]);
    float s1 = (b[0] + b[1]) + (b[2] + b[3]);
#pragma unroll
    for (int m = 1; m < 16; m <<= 1) {
      s0 += __shfl_xor(s0, m);
      s1 += __shfl_xor(s1, m);
    }
    if (g == 0) {
      const int R0 = kc * KB + 2 * cpair;
      atomicAdd(&st->mnsum[R0], s0);
      atomicAdd(&st->mnsum[R0 + 1], s1);
    }
#pragma unroll
    for (int i = 0; i < 4; ++i) {
      const int j = 4 * g + i;
      ldsB[buf][j * 20 + (((sq ^ ((j >> 3) & 3)) << 2) | c2)] = pack_bf2(a[i], b[i]);
    }
  };

  ldrows(0, va, vb);
  stage(0, 0, va, vb);
  if (CH / KB > 1) ldrows(1, va, vb);

  for (int kc = 0; kc < CH / KB; ++kc) {
    __syncthreads();
    bf16x8 afr[4];
#pragma unroll
    for (int mt = 0; mt < 4; ++mt)
      afr[mt] = *(const bf16x8*)(uT + (64 * wv + 16 * mt + r15) * CH + kc * KB + q * 8);
    bf16x8 bfr[4];
#pragma unroll
    for (int nt = 0; nt < 4; ++nt) {
      const int j = nt * 16 + r15;
      bfr[nt] = *(const bf16x8*)((const unsigned short*)ldsB[kc & 1] +
                                 (size_t)j * 40 + ((q ^ ((j >> 3) & 3)) << 3));
    }
    if (kc + 1 < CH / KB) stage(kc + 1, (kc + 1) & 1, va, vb);
    if (kc + 2 < CH / KB) ldrows(kc + 2, va, vb);
#pragma unroll
    for (int nt = 0; nt < 4; ++nt)
#pragma unroll
      for (int mt = 0; mt < 4; ++mt)
        acc[mt][nt] = __builtin_amdgcn_mfma_f32_16x16x32_bf16(afr[mt], bfr[nt], acc[mt][nt], 0, 0, 0);
  }

  // epilogue: store p', per-row raw min/max (on the stored representation)
#pragma unroll
  for (int mt = 0; mt < 4; ++mt) {
    if (ILV) {
      unsigned short us[4][4];
      float vr[4][4];
#pragma unroll
      for (int nt = 0; nt < 4; ++nt)
#pragma unroll
        for (int reg = 0; reg < 4; ++reg) {
          us[nt][reg] = f2bf(acc[mt][nt][reg]);
          vr[nt][reg] = bf2f(us[nt][reg]);
        }
#pragma unroll
      for (int reg = 0; reg < 4; ++reg) {
        float mnv = fminf(fminf(vr[0][reg], vr[1][reg]), fminf(vr[2][reg], vr[3][reg]));
        float mxv = fmaxf(fmaxf(vr[0][reg], vr[1][reg]), fmaxf(vr[2][reg], vr[3][reg]));
#pragma unroll
        for (int m = 8; m; m >>= 1) {
          mnv = fminf(mnv, __shfl_xor(mnv, m));
          mxv = fmaxf(mxv, __shfl_xor(mxv, m));
        }
        if (r15 == 0) {
          const int row = 64 * wv + 16 * mt + 4 * q + reg;
          smin[row] = mnv; smax[row] = mxv;
        }
      }
      unsigned* pq32 = (unsigned*)pqv;
      const int kp0 = 32 * wv + 8 * mt + 2 * q;
#pragma unroll
      for (int nt = 0; nt < 4; ++nt) {
        const size_t base = ((size_t)n * (CH / 2) + kp0) * HWsz + hw0 + nt * 16 + r15;
        pq32[base]        = (unsigned)us[nt][0] | ((unsigned)us[nt][1] << 16);
        pq32[base + HWsz] = (unsigned)us[nt][2] | ((unsigned)us[nt][3] << 16);
      }
    } else {
      float* pqf = (float*)pqv;
#pragma unroll
      for (int reg = 0; reg < 4; ++reg) {
        const int row = 64 * wv + 16 * mt + 4 * q + reg;
        float mnv = 1e30f, mxv = -1e30f;
        const size_t obase = ((size_t)(n * CH + row)) * HWsz + hw0;
#pragma unroll
        for (int nt = 0; nt < 4; ++nt) {
          float v = acc[mt][nt][reg];
          mnv = fminf(mnv, v); mxv = fmaxf(mxv, v);
          pqf[obase + nt * 16 + r15] = v;
        }
#pragma unroll
        for (int m = 8; m; m >>= 1) {
          mnv = fminf(mnv, __shfl_xor(mnv, m));
          mxv = fmaxf(mxv, __shfl_xor(mxv, m));
        }
        if (r15 == 0) { smin[row] = mnv; smax[row] = mxv; }
      }
    }
  }
  __syncthreads();
  atomicMin(&st->dminK[t], fkey(smin[t]));
  atomicMax(&st->dmaxK[t], fkey(smax[t]));
}

// ---- finalize: mn, poff, dmin/dmax via monotone clamp, scale ------------
__global__ void k_finalize(const float* __restrict__ u,
                           const float* __restrict__ clampv, Stats* st) {
  int t = threadIdx.x;
  __shared__ float smn[CH];
  float mnv = st->mnsum[t] * (1.f / COLS);
  st->mn[t] = mnv;
  smn[t] = mnv;
  __syncthreads();
  float acc = 0.f;
  for (int c = 0; c < CH; ++c) acc += u[c * CH + t] * smn[c];
  st->poff[t] = acc;
  float cv = clampv[t];
  st->clF[t] = cv;
  float dmin = clampf(funkey(st->dminK[t]) - acc, cv);
  float dmax = clampf(funkey(st->dmaxK[t]) - acc, cv);
  float rng = dmax - dmin;
  float sc = 0.f, iv = 0.f;
  if (rng != 0.f) { sc = 255.f / rng; iv = rng / 255.f; }
  st->dminF[t] = dmin; st->scaleF[t] = sc; st->invF[t] = iv;
}

// ---- qsum: per-row sum of dequantized q ---------------------------------
template <bool ILV>
__global__ __launch_bounds__(256) void k_qsum(const void* __restrict__ pqv,
                                              Stats* __restrict__ st) {
  __shared__ float w4a[4], w4b[4];
  const int blk = blockIdx.x;
  if (ILV) {
    const int kp = blk & (CH / 2 - 1);
    const int r0 = 2 * kp, r1 = r0 + 1;
    const float p0 = st->poff[r0], c0 = st->clF[r0], d0 = st->dminF[r0],
                sc0 = st->scaleF[r0], i0 = st->invF[r0];
    const float p1 = st->poff[r1], c1 = st->clF[r1], d1 = st->dminF[r1],
                sc1 = st->scaleF[r1], i1 = st->invF[r1];
    const uint4* p = (const uint4*)((const unsigned*)pqv + (size_t)blk * HWsz);
    float s0 = 0.f, s1 = 0.f;
    for (int i = threadIdx.x; i < HWsz / 4; i += 256) {
      const uint4 w = p[i];
      const unsigned ws[4] = {w.x, w.y, w.z, w.w};
#pragma unroll
      for (int k = 0; k < 4; ++k) {
        s0 += dq(clampf(bf2f((unsigned short)(ws[k] & 0xffffu)) - p0, c0), d0, sc0, i0);
        s1 += dq(clampf(bf2f((unsigned short)(ws[k] >> 16)) - p1, c1), d1, sc1, i1);
      }
    }
    for (int off = 32; off; off >>= 1) {
      s0 += __shfl_down(s0, off);
      s1 += __shfl_down(s1, off);
    }
    int lane = threadIdx.x & 63, wvi = threadIdx.x >> 6;
    if (!lane) { w4a[wvi] = s0; w4b[wvi] = s1; }
    __syncthreads();
    if (threadIdx.x == 0) {
      atomicAdd(&st->qsum[r0], (w4a[0] + w4a[1]) + (w4a[2] + w4a[3]));
      atomicAdd(&st->qsum[r1], (w4b[0] + w4b[1]) + (w4b[2] + w4b[3]));
    }
  } else {
    const int r = blk & (CH - 1);
    const float pf = st->poff[r], cl = st->clF[r], dmin = st->dminF[r],
                sc = st->scaleF[r], inv = st->invF[r];
    const float4* p = (const float4*)((const float*)pqv + (size_t)blk * HWsz);
    float s = 0.f;
    for (int i = threadIdx.x; i < HWsz / 4; i += 256) {
      const float4 v = p[i];
      s += dq(clampf(v.x - pf, cl), dmin, sc, inv) + dq(clampf(v.y - pf, cl), dmin, sc, inv) +
           dq(clampf(v.z - pf, cl), dmin, sc, inv) + dq(clampf(v.w - pf, cl), dmin, sc, inv);
    }
    for (int off = 32; off; off >>= 1) s += __shfl_down(s, off);
    int lane = threadIdx.x & 63, wvi = threadIdx.x >> 6;
    if (!lane) w4a[wvi] = s;
    __syncthreads();
    if (threadIdx.x == 0) atomicAdd(&st->qsum[r], (w4a[0] + w4a[1]) + (w4a[2] + w4a[3]));
  }
}

__global__ void k_corr(const float* __restrict__ u, Stats* st) {
  int t = threadIdx.x;
  __shared__ float qm[CH];
  qm[t] = st->qsum[t] * (1.f / COLS);
  __syncthreads();
  float acc = 0.f;
  for (int r = 0; r < CH; ++r) acc += u[t * CH + r] * qm[r];
  st->corr[t] = st->mn[t] - acc;
}

// ---- GEMM2: out = u @ q + corr ------------------------------------------
template <bool ILV>
__global__ __launch_bounds__(256) void k_gemm2(const void* __restrict__ pqv,
                                               Stats* __restrict__ st,
                                               float* __restrict__ out) {
  __shared__ __align__(16) unsigned ldsB[2][TN * 20];

  const int blk = blockIdx.x;
  const int n   = blk / (HWsz / TN);
  const int hw0 = (blk % (HWsz / TN)) * TN;
  const int t = threadIdx.x;
  const int lane = t & 63, wv = t >> 6;
  const int g = t & 15;
  const int kpl = t >> 4;                 // ILV staging: k-pair 0..15
  const int cpair = t >> 4;               // non-ILV staging: row-pair
  const int sq = kpl >> 2, c2 = kpl & 3;
  const int q = lane >> 4, r15 = lane & 15;

  const unsigned short* uA = st->u_bf;
  f32x4 acc[4][4] = {};

  uint4 wI;
  float4 vaF, vbF;

  auto ldrows = [&](int kc) {
    if (ILV) {
      wI = *(const uint4*)((const unsigned*)pqv +
                           ((size_t)n * (CH / 2) + kc * 16 + kpl) * HWsz + hw0 + 4 * g);
    } else {
      const float* r0 = (const float*)pqv +
                        ((size_t)(n * CH + kc * KB + 2 * cpair)) * HWsz + hw0 + 4 * g;
      vaF = *(const float4*)r0;
      vbF = *(const float4*)(r0 + HWsz);
    }
  };
  auto stage = [&](int kc, int buf) {
    const int R0 = ILV ? 2 * (kc * 16 + kpl) : kc * KB + 2 * cpair;
    const float p0 = st->poff[R0],     c0 = st->clF[R0],     d0 = st->dminF[R0],
                sc0 = st->scaleF[R0],  i0 = st->invF[R0];
    const float p1 = st->poff[R0 + 1], c1 = st->clF[R0 + 1], d1 = st->dminF[R0 + 1],
                sc1 = st->scaleF[R0 + 1], i1 = st->invF[R0 + 1];
    float lo[4], hi[4];
    if (ILV) {
      const unsigned ws[4] = {wI.x, wI.y, wI.z, wI.w};
#pragma unroll
      for (int i = 0; i < 4; ++i) {
        lo[i] = bf2f((unsigned short)(ws[i] & 0xffffu));
        hi[i] = bf2f((unsigned short)(ws[i] >> 16));
      }
    } else {
      lo[0] = vaF.x; lo[1] = vaF.y; lo[2] = vaF.z; lo[3] = vaF.w;
      hi[0] = vbF.x; hi[1] = vbF.y; hi[2] = vbF.z; hi[3] = vbF.w;
    }
#pragma unroll
    for (int i = 0; i < 4; ++i) {
      const float v0 = dq(clampf(lo[i] - p0, c0), d0, sc0, i0);
      const float v1 = dq(clampf(hi[i] - p1, c1), d1, sc1, i1);
      const int j = 4 * g + i;
      ldsB[buf][j * 20 + (((sq ^ ((j >> 3) & 3)) << 2) | c2)] = pack_bf2(v0, v1);
    }
  };

  ldrows(0);
  stage(0, 0);
  if (CH / KB > 1) ldrows(1);

  for (int kc = 0; kc < CH / KB; ++kc) {
    __syncthreads();
    bf16x8 afr[4];
#pragma unroll
    for (int mt = 0; mt < 4; ++mt)
      afr[mt] = *(const bf16x8*)(uA + (64 * wv + 16 * mt + r15) * CH + kc * KB + q * 8);
    bf16x8 bfr[4];
#pragma unroll
    for (int nt = 0; nt < 4; ++nt) {
      const int j = nt * 16 + r15;
      bfr[nt] = *(const bf16x8*)((const unsigned short*)ldsB[kc & 1] +
                                 (size_t)j * 40 + ((q ^ ((j >> 3) & 3)) << 3));
    }
    if (kc + 1 < CH / KB) stage(kc + 1, (kc + 1) & 1);
    if (kc + 2 < CH / KB) ldrows(kc + 2);
#pragma unroll
    for (int nt = 0; nt < 4; ++nt)
#pragma unroll
      for (int mt = 0; mt < 4; ++mt)
        acc[mt][nt] = __builtin_amdgcn_mfma_f32_16x16x32_bf16(afr[mt], bfr[nt], acc[mt][nt], 0, 0, 0);
  }

#pragma unroll
  for (int mt = 0; mt < 4; ++mt)
#pragma unroll
    for (int reg = 0; reg < 4; ++reg) {
      const int row = 64 * wv + 16 * mt + 4 * q + reg;
      const float cr = st->corr[row];
      const size_t obase = ((size_t)(n * CH + row)) * HWsz + hw0;
#pragma unroll
      for (int nt = 0; nt < 4; ++nt)
        out[obase + nt * 16 + r15] = acc[mt][nt][reg] + cr;
    }
}

extern "C" void kernel_launch(void* const* d_in, const int* in_sizes, int n_in,
                              void* d_out, int out_size, void* d_ws, size_t ws_size,
                              hipStream_t stream) {
  const float* x  = (const float*)d_in[0];
  const float* u  = (const float*)d_in[1];
  const float* cv = (const float*)d_in[2];
  float* out = (float*)d_out;
  Stats* st = (Stats*)d_ws;

  const size_t pq_off = (sizeof(Stats) + 255) & ~(size_t)255;
  const bool ilv = ws_size >= pq_off + (size_t)NIMG * (CH / 2) * HWsz * 4;
  void* pq = ilv ? (void*)((char*)d_ws + pq_off) : (void*)out;

  const int gemm_blocks = NIMG * (HWsz / TN);  // 1568

  k_init<<<CH, CH, 0, stream>>>(u, st);
  if (ilv) k_gemm1<true ><<<gemm_blocks, 256, 0, stream>>>(x, st, pq);
  else     k_gemm1<false><<<gemm_blocks, 256, 0, stream>>>(x, st, pq);
  k_finalize<<<1, CH, 0, stream>>>(u, cv, st);
  if (ilv) k_qsum<true ><<<NIMG * (CH / 2), 256, 0, stream>>>(pq, st);
  else     k_qsum<false><<<NIMG * CH, 256, 0, stream>>>(pq, st);
  k_corr<<<1, CH, 0, stream>>>(u, st);
  if (ilv) k_gemm2<true ><<<gemm_blocks, 256, 0, stream>>>(pq, st, out);
  else     k_gemm2<false><<<gemm_blocks, 256, 0, stream>>>(pq, st, out);
}

// Round 3
// 329.999 us; speedup vs baseline: 1.3360x; 1.3360x over previous
//
#include <hip/hip_runtime.h>
#include <hip/hip_bf16.h>
#include <stdint.h>

#define CH    256
#define HWsz  3136
#define NIMG  32
#define COLS  (NIMG * HWsz)   // 100352
#define KB    32
#define TN    64
#define TILES (COLS / TN)     // 1568
#define PBLK  2               // tiles per block
#define GI_N  (8 * PBLK)      // 16 pipeline iterations per block

typedef float  f32x4  __attribute__((ext_vector_type(4)));
typedef __bf16 bf16x8 __attribute__((ext_vector_type(8)));

struct Stats {
  float mnsum[CH];
  float mn[CH];
  float poff[CH];
  float clF[CH];
  unsigned dminK[CH];
  unsigned dmaxK[CH];
  float dminF[CH];
  float scaleF[CH];
  float invF[CH];
  float qsum[CH];
  float corr[CH];
  unsigned short u_bf[CH * CH];   // u row-major (A for GEMM2)
  unsigned short uT_bf[CH * CH];  // u transposed (A for GEMM1)
};

__device__ __forceinline__ unsigned short f2bf(float f) {
  union { float f; unsigned u; } v; v.f = f;
  unsigned r = v.u + 0x7fffu + ((v.u >> 16) & 1u);  // RNE
  return (unsigned short)(r >> 16);
}
__device__ __forceinline__ float bf2f(unsigned short b) {
  union { unsigned u; float f; } v; v.u = ((unsigned)b) << 16;
  return v.f;
}
__device__ __forceinline__ unsigned pack_bf2(float a, float b) {
  return (unsigned)f2bf(a) | ((unsigned)f2bf(b) << 16);
}
__device__ __forceinline__ unsigned fkey(float f) {
  unsigned u = __float_as_uint(f);
  return (u & 0x80000000u) ? ~u : (u | 0x80000000u);
}
__device__ __forceinline__ float funkey(unsigned k) {
  unsigned u = (k & 0x80000000u) ? (k & 0x7fffffffu) : ~k;
  return __uint_as_float(u);
}
__device__ __forceinline__ float clampf(float v, float c) {
  return fminf(fmaxf(v, -c), c);
}
__device__ __forceinline__ float dq(float v, float dmin, float sc, float inv) {
  return sc == 0.f ? v : fmaf(rintf((v - dmin) * sc), inv, dmin);
}

// ---- init ---------------------------------------------------------------
__global__ void k_init(const float* __restrict__ u, Stats* st) {
  int b = blockIdx.x, t = threadIdx.x;
  st->u_bf[b * CH + t]  = f2bf(u[b * CH + t]);
  st->uT_bf[b * CH + t] = f2bf(u[t * CH + b]);
  if (b == 0) {
    st->mnsum[t] = 0.f;
    st->qsum[t]  = 0.f;
    st->dminK[t] = 0xFFFFFFFFu;
    st->dmaxK[t] = 0u;
  }
}

// ---- GEMM1: p' = uT @ relu(x) raw (bf16 ILV store), fused relu-sums (reg)
// + per-row raw min/max. 2 tiles/block, 3-deep reg pipeline, LDS dbuf.
__global__ __launch_bounds__(256) void k_gemm1(const float* __restrict__ x,
                                               Stats* __restrict__ st,
                                               unsigned* __restrict__ pq,
                                               long nstride) {
  __shared__ __align__(16) unsigned ldsB[2][TN * 20];  // 10240 B
  __shared__ float smin[CH];                           // 1 KB
  __shared__ float smax[CH];                           // 1 KB
  __shared__ float scr[CH][17];                        // 17408 B

  const int t = threadIdx.x;
  const int lane = t & 63, wv = t >> 6;
  const int g = t & 15, cpair = t >> 4;
  const int c2 = cpair & 3;
  const int q = lane >> 4, r15 = lane & 15;
  const int wsw = (((wv ^ ((g >> 1) & 3)) << 2) | c2);  // write swizzle (j>>3 == g>>1)

  const int t0 = blockIdx.x * PBLK;
  const unsigned short* uT = st->uT_bf;

  smin[t] = 1e30f;
  smax[t] = -1e30f;

  f32x4 acc[4][4] = {};
  float4 rA[3], rB[3];
  float relp[8][2] = {};

  auto ld = [&](int gi, int slot) {
    const int tile = t0 + (gi >> 3), kc = gi & 7;
    const int n = tile / 49, hw0 = (tile % 49) * TN;
    const float* p = x + (size_t)n * CH * HWsz + (size_t)(kc * KB + 2 * cpair) * HWsz + hw0 + 4 * g;
    rA[slot] = *(const float4*)p;
    rB[slot] = *(const float4*)(p + HWsz);
  };
  auto stage = [&](int gi, int slot) {
    const int kc = gi & 7, buf = gi & 1;
    const float a[4] = {fmaxf(rA[slot].x, 0.f), fmaxf(rA[slot].y, 0.f),
                        fmaxf(rA[slot].z, 0.f), fmaxf(rA[slot].w, 0.f)};
    const float b[4] = {fmaxf(rB[slot].x, 0.f), fmaxf(rB[slot].y, 0.f),
                        fmaxf(rB[slot].z, 0.f), fmaxf(rB[slot].w, 0.f)};
    relp[kc][0] += (a[0] + a[1]) + (a[2] + a[3]);
    relp[kc][1] += (b[0] + b[1]) + (b[2] + b[3]);
#pragma unroll
    for (int i = 0; i < 4; ++i)
      ldsB[buf][(4 * g + i) * 20 + wsw] = pack_bf2(a[i], b[i]);
  };
  auto epi = [&](int tile) {
    const int n = tile / 49, hw0 = (tile % 49) * TN;
#pragma unroll
    for (int mt = 0; mt < 4; ++mt) {
      const int kp0 = 32 * wv + 8 * mt + 2 * q;
      float mn4[4], mx4[4];
#pragma unroll
      for (int nt = 0; nt < 4; ++nt) {
        const unsigned w01 = pack_bf2(acc[mt][nt][0], acc[mt][nt][1]);
        const unsigned w23 = pack_bf2(acc[mt][nt][2], acc[mt][nt][3]);
        const size_t base = (size_t)n * nstride + (size_t)kp0 * HWsz + hw0 + nt * 16 + r15;
        pq[base]        = w01;
        pq[base + HWsz] = w23;
        const float v[4] = {bf2f((unsigned short)(w01 & 0xffffu)), bf2f((unsigned short)(w01 >> 16)),
                            bf2f((unsigned short)(w23 & 0xffffu)), bf2f((unsigned short)(w23 >> 16))};
#pragma unroll
        for (int reg = 0; reg < 4; ++reg) {
          if (nt == 0) { mn4[reg] = v[reg]; mx4[reg] = v[reg]; }
          else { mn4[reg] = fminf(mn4[reg], v[reg]); mx4[reg] = fmaxf(mx4[reg], v[reg]); }
        }
      }
#pragma unroll
      for (int reg = 0; reg < 4; ++reg) {
#pragma unroll
        for (int m = 8; m; m >>= 1) {
          mn4[reg] = fminf(mn4[reg], __shfl_xor(mn4[reg], m));
          mx4[reg] = fmaxf(mx4[reg], __shfl_xor(mx4[reg], m));
        }
        if (r15 == 0) {
          const int row = 64 * wv + 16 * mt + 4 * q + reg;
          smin[row] = fminf(smin[row], mn4[reg]);
          smax[row] = fmaxf(smax[row], mx4[reg]);
        }
      }
    }
  };

  ld(0, 0); ld(1, 1); ld(2, 2);
  stage(0, 0);

#pragma unroll
  for (int gi = 0; gi < GI_N; ++gi) {
    __syncthreads();
    const int kc = gi & 7;
    bf16x8 afr[4];
#pragma unroll
    for (int mt = 0; mt < 4; ++mt)
      afr[mt] = *(const bf16x8*)(uT + (64 * wv + 16 * mt + r15) * CH + kc * KB + q * 8);
    bf16x8 bfr[4];
#pragma unroll
    for (int nt = 0; nt < 4; ++nt) {
      const int j = nt * 16 + r15;
      bfr[nt] = *(const bf16x8*)((const unsigned short*)ldsB[gi & 1] +
                                 (size_t)j * 40 + ((q ^ ((j >> 3) & 3)) << 3));
    }
    if (gi + 3 < GI_N) ld(gi + 3, (gi + 3) % 3);
    if (gi + 1 < GI_N) stage(gi + 1, (gi + 1) % 3);
#pragma unroll
    for (int nt = 0; nt < 4; ++nt)
#pragma unroll
      for (int mt = 0; mt < 4; ++mt)
        acc[mt][nt] = __builtin_amdgcn_mfma_f32_16x16x32_bf16(afr[mt], bfr[nt], acc[mt][nt], 0, 0, 0);
    if ((gi & 7) == 7) {
      epi(t0 + (gi >> 3));
#pragma unroll
      for (int mt = 0; mt < 4; ++mt)
#pragma unroll
        for (int nt = 0; nt < 4; ++nt)
          acc[mt][nt] = (f32x4)(0.f);
    }
  }

  // relu-sum reduction: regs -> LDS transpose -> one atomic per row per block
  __syncthreads();
#pragma unroll
  for (int kc = 0; kc < 8; ++kc) {
    scr[kc * 32 + 2 * cpair + 0][g] = relp[kc][0];
    scr[kc * 32 + 2 * cpair + 1][g] = relp[kc][1];
  }
  __syncthreads();
  float s = 0.f;
#pragma unroll
  for (int i = 0; i < 16; ++i) s += scr[t][i];
  atomicAdd(&st->mnsum[t], s);
  atomicMin(&st->dminK[t], fkey(smin[t]));
  atomicMax(&st->dmaxK[t], fkey(smax[t]));
}

// ---- finalize: mn, poff, dmin/dmax via monotone clamp, scale ------------
__global__ void k_finalize(const float* __restrict__ u,
                           const float* __restrict__ clampv, Stats* st) {
  int t = threadIdx.x;
  __shared__ float smn[CH];
  float mnv = st->mnsum[t] * (1.f / COLS);
  st->mn[t] = mnv;
  smn[t] = mnv;
  __syncthreads();
  float acc = 0.f;
  for (int c = 0; c < CH; ++c) acc += u[c * CH + t] * smn[c];
  st->poff[t] = acc;
  float cv = clampv[t];
  st->clF[t] = cv;
  float dmin = clampf(funkey(st->dminK[t]) - acc, cv);
  float dmax = clampf(funkey(st->dmaxK[t]) - acc, cv);
  float rng = dmax - dmin;
  float sc = 0.f, iv = 0.f;
  if (rng != 0.f) { sc = 255.f / rng; iv = rng / 255.f; }
  st->dminF[t] = dmin; st->scaleF[t] = sc; st->invF[t] = iv;
}

// ---- qsum: per-row sum of dequantized q ---------------------------------
__global__ __launch_bounds__(256) void k_qsum(const unsigned* __restrict__ pq,
                                              long nstride,
                                              Stats* __restrict__ st) {
  __shared__ float w4a[4], w4b[4];
  const int blk = blockIdx.x;
  const int n = blk >> 7, kp = blk & 127;
  const int r0 = 2 * kp, r1 = r0 + 1;
  const float p0 = st->poff[r0], c0 = st->clF[r0], d0 = st->dminF[r0],
              sc0 = st->scaleF[r0], i0 = st->invF[r0];
  const float p1 = st->poff[r1], c1 = st->clF[r1], d1 = st->dminF[r1],
              sc1 = st->scaleF[r1], i1 = st->invF[r1];
  const uint4* p = (const uint4*)(pq + (size_t)n * nstride + (size_t)kp * HWsz);
  float s0 = 0.f, s1 = 0.f;
  for (int i = threadIdx.x; i < HWsz / 4; i += 256) {
    const uint4 w = p[i];
    const unsigned ws[4] = {w.x, w.y, w.z, w.w};
#pragma unroll
    for (int k = 0; k < 4; ++k) {
      s0 += dq(clampf(bf2f((unsigned short)(ws[k] & 0xffffu)) - p0, c0), d0, sc0, i0);
      s1 += dq(clampf(bf2f((unsigned short)(ws[k] >> 16)) - p1, c1), d1, sc1, i1);
    }
  }
  for (int off = 32; off; off >>= 1) {
    s0 += __shfl_down(s0, off);
    s1 += __shfl_down(s1, off);
  }
  int lane = threadIdx.x & 63, wvi = threadIdx.x >> 6;
  if (!lane) { w4a[wvi] = s0; w4b[wvi] = s1; }
  __syncthreads();
  if (threadIdx.x == 0) {
    atomicAdd(&st->qsum[r0], (w4a[0] + w4a[1]) + (w4a[2] + w4a[3]));
    atomicAdd(&st->qsum[r1], (w4b[0] + w4b[1]) + (w4b[2] + w4b[3]));
  }
}

__global__ void k_corr(const float* __restrict__ u, Stats* st) {
  int t = threadIdx.x;
  __shared__ float qm[CH];
  qm[t] = st->qsum[t] * (1.f / COLS);
  __syncthreads();
  float acc = 0.f;
  for (int r = 0; r < CH; ++r) acc += u[t * CH + r] * qm[r];
  st->corr[t] = st->mn[t] - acc;
}

// ---- GEMM2: out = u @ q + corr ------------------------------------------
__global__ __launch_bounds__(256) void k_gemm2(const unsigned* __restrict__ pq,
                                               long nstride,
                                               Stats* __restrict__ st,
                                               float* __restrict__ out) {
  __shared__ __align__(16) unsigned ldsB[2][TN * 20];
  __shared__ float pf[CH], cl[CH], dm[CH], sc[CH], iv[CH], co[CH];

  const int t = threadIdx.x;
  const int lane = t & 63, wv = t >> 6;
  const int g = t & 15, kpl = t >> 4;
  const int c2 = kpl & 3;
  const int q = lane >> 4, r15 = lane & 15;
  const int wsw = (((wv ^ ((g >> 1) & 3)) << 2) | c2);

  const int t0 = blockIdx.x * PBLK;
  const unsigned short* uA = st->u_bf;

  pf[t] = st->poff[t]; cl[t] = st->clF[t]; dm[t] = st->dminF[t];
  sc[t] = st->scaleF[t]; iv[t] = st->invF[t]; co[t] = st->corr[t];
  __syncthreads();

  f32x4 acc[4][4] = {};
  uint4 rW[3];

  auto ld = [&](int gi, int slot) {
    const int tile = t0 + (gi >> 3), kc = gi & 7;
    const int n = tile / 49, hw0 = (tile % 49) * TN;
    rW[slot] = *(const uint4*)(pq + (size_t)n * nstride + (size_t)(kc * 16 + kpl) * HWsz + hw0 + 4 * g);
  };
  auto stage = [&](int gi, int slot) {
    const int kc = gi & 7, buf = gi & 1;
    const int R0 = 2 * (kc * 16 + kpl);
    const float p0 = pf[R0],     q0 = cl[R0],     e0 = dm[R0],     s0 = sc[R0],     v0 = iv[R0];
    const float p1 = pf[R0 + 1], q1 = cl[R0 + 1], e1 = dm[R0 + 1], s1 = sc[R0 + 1], v1 = iv[R0 + 1];
    const unsigned ws[4] = {rW[slot].x, rW[slot].y, rW[slot].z, rW[slot].w};
#pragma unroll
    for (int i = 0; i < 4; ++i) {
      const float a = dq(clampf(bf2f((unsigned short)(ws[i] & 0xffffu)) - p0, q0), e0, s0, v0);
      const float b = dq(clampf(bf2f((unsigned short)(ws[i] >> 16)) - p1, q1), e1, s1, v1);
      ldsB[buf][(4 * g + i) * 20 + wsw] = pack_bf2(a, b);
    }
  };
  auto epi = [&](int tile) {
    const int n = tile / 49, hw0 = (tile % 49) * TN;
#pragma unroll
    for (int mt = 0; mt < 4; ++mt)
#pragma unroll
      for (int reg = 0; reg < 4; ++reg) {
        const int row = 64 * wv + 16 * mt + 4 * q + reg;
        const float cr = co[row];
        const size_t obase = ((size_t)n * CH + row) * HWsz + hw0;
#pragma unroll
        for (int nt = 0; nt < 4; ++nt)
          out[obase + nt * 16 + r15] = acc[mt][nt][reg] + cr;
      }
  };

  ld(0, 0); ld(1, 1); ld(2, 2);
  stage(0, 0);

#pragma unroll
  for (int gi = 0; gi < GI_N; ++gi) {
    __syncthreads();
    const int kc = gi & 7;
    bf16x8 afr[4];
#pragma unroll
    for (int mt = 0; mt < 4; ++mt)
      afr[mt] = *(const bf16x8*)(uA + (64 * wv + 16 * mt + r15) * CH + kc * KB + q * 8);
    bf16x8 bfr[4];
#pragma unroll
    for (int nt = 0; nt < 4; ++nt) {
      const int j = nt * 16 + r15;
      bfr[nt] = *(const bf16x8*)((const unsigned short*)ldsB[gi & 1] +
                                 (size_t)j * 40 + ((q ^ ((j >> 3) & 3)) << 3));
    }
    if (gi + 3 < GI_N) ld(gi + 3, (gi + 3) % 3);
    if (gi + 1 < GI_N) stage(gi + 1, (gi + 1) % 3);
#pragma unroll
    for (int nt = 0; nt < 4; ++nt)
#pragma unroll
      for (int mt = 0; mt < 4; ++mt)
        acc[mt][nt] = __builtin_amdgcn_mfma_f32_16x16x32_bf16(afr[mt], bfr[nt], acc[mt][nt], 0, 0, 0);
    if ((gi & 7) == 7) {
      epi(t0 + (gi >> 3));
#pragma unroll
      for (int mt = 0; mt < 4; ++mt)
#pragma unroll
        for (int nt = 0; nt < 4; ++nt)
          acc[mt][nt] = (f32x4)(0.f);
    }
  }
}

extern "C" void kernel_launch(void* const* d_in, const int* in_sizes, int n_in,
                              void* d_out, int out_size, void* d_ws, size_t ws_size,
                              hipStream_t stream) {
  const float* x  = (const float*)d_in[0];
  const float* u  = (const float*)d_in[1];
  const float* cv = (const float*)d_in[2];
  float* out = (float*)d_out;
  Stats* st = (Stats*)d_ws;

  const size_t pq_off = (sizeof(Stats) + 255) & ~(size_t)255;
  const size_t pq_bytes = (size_t)NIMG * (CH / 2) * HWsz * 4;
  unsigned* pq;
  long nstride;
  if (ws_size >= pq_off + pq_bytes) {
    pq = (unsigned*)((char*)d_ws + pq_off);
    nstride = (long)(CH / 2) * HWsz;
  } else {
    // host pq in the upper half-rows of each image's slab of d_out.
    // Safe: each gemm2 block reads only its own (n, col-range) pq slice and
    // writes only that slice's out rows, after all its reads completed.
    pq = (unsigned*)d_out + (size_t)(CH / 2) * HWsz;
    nstride = (long)CH * HWsz;
  }

  const int gemm_blocks = TILES / PBLK;  // 784

  k_init<<<CH, CH, 0, stream>>>(u, st);
  k_gemm1<<<gemm_blocks, 256, 0, stream>>>(x, st, pq, nstride);
  k_finalize<<<1, CH, 0, stream>>>(u, cv, st);
  k_qsum<<<NIMG * (CH / 2), 256, 0, stream>>>(pq, nstride, st);
  k_corr<<<1, CH, 0, stream>>>(u, st);
  k_gemm2<<<gemm_blocks, 256, 0, stream>>>(pq, nstride, st, out);
}